// Round 3
// baseline (680.749 us; speedup 1.0000x reference)
//
#include <hip/hip_runtime.h>
#include <math.h>

#define N_NODES 100000
#define N_EDGES 3200000
#define EPS_F 1e-6f

// ws layout (floats):
//   [0]      : (reserved)
//   [1..4]   : sum(p0), sum(p1), sum(p0^2), sum(p1^2)
//   [5]      : sum(node_sum^2)
//   [64 ...] : node_sum replicas: REP replicas, node i of replica r at
//              ws[64 + r*N_NODES*STRIDE + i*STRIDE]
#define WS_NODE_OFF 64

__device__ __forceinline__ float wave_reduce(float v) {
    #pragma unroll
    for (int off = 32; off > 0; off >>= 1) v += __shfl_down(v, off, 64);
    return v;
}

// Agent-scope native fp32 atomic (memory-side RMW) — for the tiny scalar accs.
__device__ __forceinline__ void fadd_agent(float* p, float v) {
    unsafeAtomicAdd(p, v);
}

// Workgroup-scope fp32 atomic: performed in the XCD-local L2 (no bypass).
// Safe only if ALL updaters of the address run on the same XCD.
__device__ __forceinline__ void fadd_wg(float* p, float v) {
    __hip_atomic_fetch_add(p, v, __ATOMIC_RELAXED, __HIP_MEMORY_SCOPE_WORKGROUP);
}

__device__ __forceinline__ int get_xcc_id() {
    int x;
    asm("s_getreg_b32 %0, hwreg(HW_REG_XCC_ID, 0, 32)" : "=s"(x));
    return x & 7;
}

template <int REP, int STRIDE, bool WG>
__global__ __launch_bounds__(256) void edge_kernel(
    const float*  __restrict__ nf,      // node_features [N_NODES,4]
    const void*   __restrict__ eidx,    // edge_index [2, N_EDGES], int32 or int64
    const float*  __restrict__ logits,  // [N_EDGES]
    const float2* __restrict__ params,  // [N_EDGES, 2]
    float*        __restrict__ ws)
{
    const int*       i32 = (const int*)eidx;
    const long long* i64 = (const long long*)eidx;

    // Detect index dtype (uniform, cheap): int64 values < 2^31 have zero hi
    // words at every odd int32 slot; int32 has random node ids there.
    int any = 0;
    #pragma unroll
    for (int k = 1; k < 32; k += 2) any |= i32[k];
    const bool is32 = (any != 0);

    float* node_base = ws + WS_NODE_OFF +
        (size_t)(WG ? get_xcc_id() : 0) * ((size_t)N_NODES * STRIDE);
    float* acc = ws + 1;

    float s0 = 0.f, s1 = 0.f, q0 = 0.f, q1 = 0.f;
    const int tid    = blockIdx.x * blockDim.x + threadIdx.x;
    const int stride = gridDim.x * blockDim.x;

    for (int i = tid; i < N_EDGES; i += stride) {
        int src, dst;
        if (is32) {
            src = i32[i];
            dst = i32[N_EDGES + i];
        } else {
            src = (int)i64[i];
            dst = (int)i64[N_EDGES + i];
        }
        const float2 ep = params[i];
        const float  lg = logits[i];
        const float  vs = nf[src * 4];
        const float  vd = nf[dst * 4];

        const float p   = 1.0f / (1.0f + __expf(-lg));
        const float cur = fabsf(vs - vd) / (ep.x + ep.y + EPS_F) * p;

        if (WG) {
            fadd_wg(node_base + (size_t)dst * STRIDE,  cur);
            fadd_wg(node_base + (size_t)src * STRIDE, -cur);
        } else {
            fadd_agent(node_base + (size_t)dst * STRIDE,  cur);
            fadd_agent(node_base + (size_t)src * STRIDE, -cur);
        }

        s0 += ep.x; s1 += ep.y;
        q0 += ep.x * ep.x; q1 += ep.y * ep.y;
    }

    s0 = wave_reduce(s0);
    s1 = wave_reduce(s1);
    q0 = wave_reduce(q0);
    q1 = wave_reduce(q1);
    if ((threadIdx.x & 63) == 0) {
        fadd_agent(acc + 0, s0);
        fadd_agent(acc + 1, s1);
        fadd_agent(acc + 2, q0);
        fadd_agent(acc + 3, q1);
    }
}

template <int REP, int STRIDE>
__global__ __launch_bounds__(256) void kcl_kernel(float* __restrict__ ws) {
    const float* node_base = ws + WS_NODE_OFF;
    float acc = 0.f;
    const int tid    = blockIdx.x * blockDim.x + threadIdx.x;
    const int stride = gridDim.x * blockDim.x;
    for (int i = tid; i < N_NODES; i += stride) {
        float s = 0.f;
        #pragma unroll
        for (int r = 0; r < REP; ++r)
            s += node_base[(size_t)r * N_NODES * STRIDE + (size_t)i * STRIDE];
        acc += s * s;
    }
    acc = wave_reduce(acc);
    if ((threadIdx.x & 63) == 0) fadd_agent(ws + 5, acc);
}

__global__ void final_kernel(const float* __restrict__ ws, float* __restrict__ out) {
    const float s0 = ws[1], s1 = ws[2], q0 = ws[3], q1 = ws[4], k = ws[5];
    const float n  = (float)N_EDGES;
    const float var0 = (q0 - s0 * s0 / n) / (n - 1.0f);
    const float var1 = (q1 - s1 * s1 / n) / (n - 1.0f);
    out[0] = k / (float)N_NODES + 0.5f * (var0 + var1);
}

extern "C" void kernel_launch(void* const* d_in, const int* in_sizes, int n_in,
                              void* d_out, int out_size, void* d_ws, size_t ws_size,
                              hipStream_t stream) {
    const float*  nf     = (const float*)d_in[0];
    const void*   eidx   = d_in[1];
    const float*  logits = (const float*)d_in[2];
    const float2* params = (const float2*)d_in[3];
    float* ws  = (float*)d_ws;
    float* out = (float*)d_out;

    const size_t need_full = 256 + (size_t)8 * N_NODES * 4 * sizeof(float); // ~12.8 MB

    if (ws_size >= need_full) {
        // 8 XCD-local replicas, 16 B node stride, workgroup-scope L2 atomics.
        hipMemsetAsync(d_ws, 0, need_full, stream);
        edge_kernel<8, 4, true><<<2048, 256, 0, stream>>>(nf, eidx, logits, params, ws);
        kcl_kernel<8, 4><<<200, 256, 0, stream>>>(ws);
    } else {
        // Fallback: single copy, agent-scope memory-side atomics.
        hipMemsetAsync(d_ws, 0, 256 + (size_t)N_NODES * sizeof(float), stream);
        edge_kernel<1, 1, false><<<2048, 256, 0, stream>>>(nf, eidx, logits, params, ws);
        kcl_kernel<1, 1><<<200, 256, 0, stream>>>(ws);
    }

    final_kernel<<<1, 1, 0, stream>>>(ws, out);
}

// Round 4
// 627.112 us; speedup vs baseline: 1.0855x; 1.0855x over previous
//
#include <hip/hip_runtime.h>
#include <math.h>

#define N_NODES 100000
#define N_EDGES 3200000
#define EPS_F 1e-6f

#define NSLICE  8
#define SLICE_N 12500                     // nodes per slice (8*12500 = 100000)
#define NCHUNK  64
#define CHUNK_E (N_EDGES / NCHUNK)        // 50000 exactly

// ws layout (float indices):
//   [1..4]   : sum(p0), sum(p1), sum(p0^2), sum(p1^2)
//   [5]      : sum(node_sum^2)
//   CUR_OFF  : cur[N_EDGES]                       (12.8 MB)
//   IDX_OFF  : packed int2 (src,dst)[N_EDGES]     (25.6 MB)
//   PART_OFF : partials[NCHUNK][N_NODES]          (25.6 MB)
#define CUR_OFF   64
#define IDX_OFF   (CUR_OFF + N_EDGES)
#define PART_OFF  (IDX_OFF + 2 * N_EDGES)
#define WS_FLOATS (PART_OFF + NCHUNK * N_NODES)

__device__ __forceinline__ float wave_reduce(float v) {
    #pragma unroll
    for (int off = 32; off > 0; off >>= 1) v += __shfl_down(v, off, 64);
    return v;
}

__device__ __forceinline__ void fadd_agent(float* p, float v) {
    unsafeAtomicAdd(p, v);   // only used for ~10k scalar-acc updates
}

// ---------------- pass A: per-edge compute + pack ----------------
__global__ __launch_bounds__(256) void prep_kernel(
    const float*  __restrict__ nf,
    const void*   __restrict__ eidx,
    const float*  __restrict__ logits,
    const float2* __restrict__ params,
    float*        __restrict__ ws)
{
    const int*       i32 = (const int*)eidx;
    const long long* i64 = (const long long*)eidx;

    // int64 values < 2^31 have zero hi-words at every odd int32 slot;
    // int32 has random node ids there (16 zeros ~ impossible).
    int any = 0;
    #pragma unroll
    for (int k = 1; k < 32; k += 2) any |= i32[k];
    const bool is32 = (any != 0);

    float* cur_out = ws + CUR_OFF;
    int2*  idx_out = (int2*)(ws + IDX_OFF);
    float* acc     = ws + 1;

    float s0 = 0.f, s1 = 0.f, q0 = 0.f, q1 = 0.f;
    const int tid    = blockIdx.x * blockDim.x + threadIdx.x;
    const int stride = gridDim.x * blockDim.x;

    for (int i = tid; i < N_EDGES; i += stride) {
        int src, dst;
        if (is32) {
            src = i32[i];
            dst = i32[N_EDGES + i];
        } else {
            src = (int)i64[i];
            dst = (int)i64[N_EDGES + i];
        }
        const float2 ep = params[i];
        const float  lg = logits[i];
        const float  vs = nf[src * 4];
        const float  vd = nf[dst * 4];

        const float p   = 1.0f / (1.0f + __expf(-lg));
        const float cur = fabsf(vs - vd) / (ep.x + ep.y + EPS_F) * p;

        cur_out[i] = cur;
        idx_out[i] = make_int2(src, dst);

        s0 += ep.x; s1 += ep.y;
        q0 += ep.x * ep.x; q1 += ep.y * ep.y;
    }

    s0 = wave_reduce(s0);
    s1 = wave_reduce(s1);
    q0 = wave_reduce(q0);
    q1 = wave_reduce(q1);
    if ((threadIdx.x & 63) == 0) {
        fadd_agent(acc + 0, s0);
        fadd_agent(acc + 1, s1);
        fadd_agent(acc + 2, q0);
        fadd_agent(acc + 3, q1);
    }
}

// ---------------- pass B: LDS-binned scatter, no global atomics ----------------
__global__ __launch_bounds__(256) void scatter_kernel(float* __restrict__ ws)
{
    __shared__ float bins[SLICE_N];   // 50 KB

    const int s  = blockIdx.x & (NSLICE - 1);   // slice
    const int c  = blockIdx.x >> 3;             // edge chunk
    const int lo = s * SLICE_N;

    for (int j = threadIdx.x; j < SLICE_N; j += 256) bins[j] = 0.f;
    __syncthreads();

    const int2*  idx = (const int2*)(ws + IDX_OFF);
    const float* cur = ws + CUR_OFF;

    const int e0 = c * CHUNK_E;
    for (int e = e0 + threadIdx.x; e < e0 + CHUNK_E; e += 256) {
        const int2  sd = idx[e];
        const float v  = cur[e];
        const unsigned ds = (unsigned)(sd.y - lo);
        const unsigned ss = (unsigned)(sd.x - lo);
        if (ds < SLICE_N) atomicAdd(&bins[ds],  v);   // ds_add_f32
        if (ss < SLICE_N) atomicAdd(&bins[ss], -v);
    }
    __syncthreads();

    float* p = ws + PART_OFF + (size_t)c * N_NODES + lo;
    for (int j = threadIdx.x; j < SLICE_N; j += 256) p[j] = bins[j];
}

// ---------------- pass C: merge partials, sum of squares ----------------
__global__ __launch_bounds__(256) void kcl_kernel(float* __restrict__ ws)
{
    const int i = blockIdx.x * blockDim.x + threadIdx.x;
    float acc = 0.f;
    if (i < N_NODES) {
        const float* p = ws + PART_OFF + i;
        float s = 0.f;
        #pragma unroll 8
        for (int c = 0; c < NCHUNK; ++c) s += p[(size_t)c * N_NODES];
        acc = s * s;
    }
    acc = wave_reduce(acc);
    if ((threadIdx.x & 63) == 0) fadd_agent(ws + 5, acc);
}

__global__ void final_kernel(const float* __restrict__ ws, float* __restrict__ out)
{
    const float s0 = ws[1], s1 = ws[2], q0 = ws[3], q1 = ws[4], k = ws[5];
    const float n  = (float)N_EDGES;
    const float var0 = (q0 - s0 * s0 / n) / (n - 1.0f);
    const float var1 = (q1 - s1 * s1 / n) / (n - 1.0f);
    out[0] = k / (float)N_NODES + 0.5f * (var0 + var1);
}

// ---------------- fallback (ws too small): agent-atomic scatter ----------------
#define FB_NODE_OFF 64
__global__ __launch_bounds__(256) void edge_kernel_fb(
    const float*  __restrict__ nf,
    const void*   __restrict__ eidx,
    const float*  __restrict__ logits,
    const float2* __restrict__ params,
    float*        __restrict__ ws)
{
    const int*       i32 = (const int*)eidx;
    const long long* i64 = (const long long*)eidx;
    int any = 0;
    #pragma unroll
    for (int k = 1; k < 32; k += 2) any |= i32[k];
    const bool is32 = (any != 0);

    float* node_sum = ws + FB_NODE_OFF;
    float* acc      = ws + 1;

    float s0 = 0.f, s1 = 0.f, q0 = 0.f, q1 = 0.f;
    const int tid    = blockIdx.x * blockDim.x + threadIdx.x;
    const int stride = gridDim.x * blockDim.x;
    for (int i = tid; i < N_EDGES; i += stride) {
        int src, dst;
        if (is32) { src = i32[i]; dst = i32[N_EDGES + i]; }
        else      { src = (int)i64[i]; dst = (int)i64[N_EDGES + i]; }
        const float2 ep = params[i];
        const float  p  = 1.0f / (1.0f + __expf(-logits[i]));
        const float cur = fabsf(nf[src * 4] - nf[dst * 4]) / (ep.x + ep.y + EPS_F) * p;
        fadd_agent(node_sum + dst,  cur);
        fadd_agent(node_sum + src, -cur);
        s0 += ep.x; s1 += ep.y; q0 += ep.x * ep.x; q1 += ep.y * ep.y;
    }
    s0 = wave_reduce(s0); s1 = wave_reduce(s1);
    q0 = wave_reduce(q0); q1 = wave_reduce(q1);
    if ((threadIdx.x & 63) == 0) {
        fadd_agent(acc + 0, s0); fadd_agent(acc + 1, s1);
        fadd_agent(acc + 2, q0); fadd_agent(acc + 3, q1);
    }
}

__global__ __launch_bounds__(256) void kcl_kernel_fb(float* __restrict__ ws)
{
    const float* node_sum = ws + FB_NODE_OFF;
    float acc = 0.f;
    const int tid    = blockIdx.x * blockDim.x + threadIdx.x;
    const int stride = gridDim.x * blockDim.x;
    for (int i = tid; i < N_NODES; i += stride) {
        const float v = node_sum[i];
        acc += v * v;
    }
    acc = wave_reduce(acc);
    if ((threadIdx.x & 63) == 0) fadd_agent(ws + 5, acc);
}

extern "C" void kernel_launch(void* const* d_in, const int* in_sizes, int n_in,
                              void* d_out, int out_size, void* d_ws, size_t ws_size,
                              hipStream_t stream) {
    const float*  nf     = (const float*)d_in[0];
    const void*   eidx   = d_in[1];
    const float*  logits = (const float*)d_in[2];
    const float2* params = (const float2*)d_in[3];
    float* ws  = (float*)d_ws;
    float* out = (float*)d_out;

    const size_t need = (size_t)WS_FLOATS * sizeof(float);   // ~64.3 MB

    if (ws_size >= need) {
        // Zero only the scalar-acc header; cur/idx/partials are fully written.
        hipMemsetAsync(d_ws, 0, 256, stream);
        prep_kernel<<<2048, 256, 0, stream>>>(nf, eidx, logits, params, ws);
        scatter_kernel<<<NCHUNK * NSLICE, 256, 0, stream>>>(ws);
        kcl_kernel<<<(N_NODES + 255) / 256, 256, 0, stream>>>(ws);
    } else {
        hipMemsetAsync(d_ws, 0, 256 + (size_t)N_NODES * sizeof(float), stream);
        edge_kernel_fb<<<2048, 256, 0, stream>>>(nf, eidx, logits, params, ws);
        kcl_kernel_fb<<<200, 256, 0, stream>>>(ws);
    }

    final_kernel<<<1, 1, 0, stream>>>(ws, out);
}

// Round 5
// 494.123 us; speedup vs baseline: 1.3777x; 1.2691x over previous
//
#include <hip/hip_runtime.h>
#include <math.h>

#define N_NODES 100000
#define N_EDGES 3200000
#define EPS_F 1e-6f

#define NSLICE  8
#define SLICE_N 12500                     // nodes per slice (8*12500 = 100000)
#define NCHUNK  64
#define CHUNK_E (N_EDGES / NCHUNK)        // 50000 exactly

// prep batching: J edges per thread, static trip count for load batching
#define PREP_J   8
#define PREP_EPB (256 * PREP_J)           // 2048 edges per block

// ws layout (float indices):
//   [1..4]   : sum(p0), sum(p1), sum(p0^2), sum(p1^2)
//   [5]      : sum(node_sum^2)
//   CUR_OFF  : cur[N_EDGES]                       (12.8 MB)
//   IDX_OFF  : packed int2 (src,dst)[N_EDGES]     (25.6 MB)
//   PART_OFF : partials[NCHUNK][N_NODES]          (25.6 MB)
#define CUR_OFF   64
#define IDX_OFF   (CUR_OFF + N_EDGES)
#define PART_OFF  (IDX_OFF + 2 * N_EDGES)
#define WS_FLOATS (PART_OFF + NCHUNK * N_NODES)

__device__ __forceinline__ float wave_reduce(float v) {
    #pragma unroll
    for (int off = 32; off > 0; off >>= 1) v += __shfl_down(v, off, 64);
    return v;
}

__device__ __forceinline__ void fadd_agent(float* p, float v) {
    unsafeAtomicAdd(p, v);   // only scalar-acc updates (~10k total)
}

// ---------------- pass A: per-edge compute + pack, ILP-batched ----------------
__global__ __launch_bounds__(256) void prep_kernel(
    const float*  __restrict__ nf,
    const void*   __restrict__ eidx,
    const float*  __restrict__ logits,
    const float2* __restrict__ params,
    float*        __restrict__ ws)
{
    const int*       i32 = (const int*)eidx;
    const long long* i64 = (const long long*)eidx;

    // int64 values < 2^31 have zero hi-words at every odd int32 slot;
    // int32 has random node ids there (16 zeros ~ impossible).
    int any = 0;
    #pragma unroll
    for (int k = 1; k < 32; k += 2) any |= i32[k];
    const bool is32 = (any != 0);

    float* cur_out = ws + CUR_OFF;
    int2*  idx_out = (int2*)(ws + IDX_OFF);
    float* acc     = ws + 1;

    const int e_base = blockIdx.x * PREP_EPB + threadIdx.x;

    int   srcv[PREP_J], dstv[PREP_J];
    float vsv[PREP_J], vdv[PREP_J], lgv[PREP_J];
    float2 epv[PREP_J];

    // Stage 1: all index loads (coalesced; clamped so loads stay unconditional)
    #pragma unroll
    for (int j = 0; j < PREP_J; ++j) {
        int e = e_base + j * 256;
        e = (e < N_EDGES) ? e : (N_EDGES - 1);
        if (is32) {
            srcv[j] = i32[e];
            dstv[j] = i32[N_EDGES + e];
        } else {
            srcv[j] = (int)i64[e];
            dstv[j] = (int)i64[N_EDGES + e];
        }
    }
    // Stage 2: 2*J independent gathers in flight
    #pragma unroll
    for (int j = 0; j < PREP_J; ++j) {
        vsv[j] = nf[srcv[j] * 4];
        vdv[j] = nf[dstv[j] * 4];
    }
    // Stage 3: streaming loads
    #pragma unroll
    for (int j = 0; j < PREP_J; ++j) {
        int e = e_base + j * 256;
        e = (e < N_EDGES) ? e : (N_EDGES - 1);
        lgv[j] = logits[e];
        epv[j] = params[e];
    }
    // Stage 4: compute + masked stores + masked sums
    float s0 = 0.f, s1 = 0.f, q0 = 0.f, q1 = 0.f;
    #pragma unroll
    for (int j = 0; j < PREP_J; ++j) {
        const int  e  = e_base + j * 256;
        const bool ok = (e < N_EDGES);
        const float2 ep = epv[j];
        const float p   = 1.0f / (1.0f + __expf(-lgv[j]));
        const float cur = fabsf(vsv[j] - vdv[j]) / (ep.x + ep.y + EPS_F) * p;
        if (ok) {
            cur_out[e] = cur;
            idx_out[e] = make_int2(srcv[j], dstv[j]);
            s0 += ep.x; s1 += ep.y;
            q0 += ep.x * ep.x; q1 += ep.y * ep.y;
        }
    }

    s0 = wave_reduce(s0);
    s1 = wave_reduce(s1);
    q0 = wave_reduce(q0);
    q1 = wave_reduce(q1);
    if ((threadIdx.x & 63) == 0) {
        fadd_agent(acc + 0, s0);
        fadd_agent(acc + 1, s1);
        fadd_agent(acc + 2, q0);
        fadd_agent(acc + 3, q1);
    }
}

// ---------------- pass B: LDS-binned scatter, 4x ILP-batched ----------------
__global__ __launch_bounds__(256) void scatter_kernel(float* __restrict__ ws)
{
    __shared__ float bins[SLICE_N];   // 50 KB

    const int s  = blockIdx.x & (NSLICE - 1);   // slice
    const int c  = blockIdx.x >> 3;             // edge chunk
    const int lo = s * SLICE_N;

    for (int j = threadIdx.x; j < SLICE_N; j += 256) bins[j] = 0.f;
    __syncthreads();

    const int2*  idx = (const int2*)(ws + IDX_OFF);
    const float* cur = ws + CUR_OFF;

    const int e0 = c * CHUNK_E;
    const int e1 = e0 + CHUNK_E;

    for (int base = e0 + threadIdx.x; base < e1; base += 1024) {
        int2  sd4[4];
        float v4[4];
        #pragma unroll
        for (int k = 0; k < 4; ++k) {
            int e = base + k * 256;
            e = (e < e1) ? e : (e1 - 1);   // clamp: loads stay unconditional
            sd4[k] = idx[e];
            v4[k]  = cur[e];
        }
        #pragma unroll
        for (int k = 0; k < 4; ++k) {
            if (base + k * 256 < e1) {
                const unsigned ds = (unsigned)(sd4[k].y - lo);
                const unsigned ss = (unsigned)(sd4[k].x - lo);
                if (ds < SLICE_N) atomicAdd(&bins[ds],  v4[k]);
                if (ss < SLICE_N) atomicAdd(&bins[ss], -v4[k]);
            }
        }
    }
    __syncthreads();

    float* p = ws + PART_OFF + (size_t)c * N_NODES + lo;
    for (int j = threadIdx.x; j < SLICE_N; j += 256) p[j] = bins[j];
}

// ---------------- pass C: merge partials, sum of squares ----------------
__global__ __launch_bounds__(256) void kcl_kernel(float* __restrict__ ws)
{
    const int i = blockIdx.x * blockDim.x + threadIdx.x;
    float acc = 0.f;
    if (i < N_NODES) {
        const float* p = ws + PART_OFF + i;
        float s = 0.f;
        #pragma unroll 8
        for (int c = 0; c < NCHUNK; ++c) s += p[(size_t)c * N_NODES];
        acc = s * s;
    }
    acc = wave_reduce(acc);
    if ((threadIdx.x & 63) == 0) fadd_agent(ws + 5, acc);
}

__global__ void final_kernel(const float* __restrict__ ws, float* __restrict__ out)
{
    const float s0 = ws[1], s1 = ws[2], q0 = ws[3], q1 = ws[4], k = ws[5];
    const float n  = (float)N_EDGES;
    const float var0 = (q0 - s0 * s0 / n) / (n - 1.0f);
    const float var1 = (q1 - s1 * s1 / n) / (n - 1.0f);
    out[0] = k / (float)N_NODES + 0.5f * (var0 + var1);
}

// ---------------- fallback (ws too small): agent-atomic scatter ----------------
#define FB_NODE_OFF 64
__global__ __launch_bounds__(256) void edge_kernel_fb(
    const float*  __restrict__ nf,
    const void*   __restrict__ eidx,
    const float*  __restrict__ logits,
    const float2* __restrict__ params,
    float*        __restrict__ ws)
{
    const int*       i32 = (const int*)eidx;
    const long long* i64 = (const long long*)eidx;
    int any = 0;
    #pragma unroll
    for (int k = 1; k < 32; k += 2) any |= i32[k];
    const bool is32 = (any != 0);

    float* node_sum = ws + FB_NODE_OFF;
    float* acc      = ws + 1;

    float s0 = 0.f, s1 = 0.f, q0 = 0.f, q1 = 0.f;
    const int tid    = blockIdx.x * blockDim.x + threadIdx.x;
    const int stride = gridDim.x * blockDim.x;
    for (int i = tid; i < N_EDGES; i += stride) {
        int src, dst;
        if (is32) { src = i32[i]; dst = i32[N_EDGES + i]; }
        else      { src = (int)i64[i]; dst = (int)i64[N_EDGES + i]; }
        const float2 ep = params[i];
        const float  p  = 1.0f / (1.0f + __expf(-logits[i]));
        const float cur = fabsf(nf[src * 4] - nf[dst * 4]) / (ep.x + ep.y + EPS_F) * p;
        fadd_agent(node_sum + dst,  cur);
        fadd_agent(node_sum + src, -cur);
        s0 += ep.x; s1 += ep.y; q0 += ep.x * ep.x; q1 += ep.y * ep.y;
    }
    s0 = wave_reduce(s0); s1 = wave_reduce(s1);
    q0 = wave_reduce(q0); q1 = wave_reduce(q1);
    if ((threadIdx.x & 63) == 0) {
        fadd_agent(acc + 0, s0); fadd_agent(acc + 1, s1);
        fadd_agent(acc + 2, q0); fadd_agent(acc + 3, q1);
    }
}

__global__ __launch_bounds__(256) void kcl_kernel_fb(float* __restrict__ ws)
{
    const float* node_sum = ws + FB_NODE_OFF;
    float acc = 0.f;
    const int tid    = blockIdx.x * blockDim.x + threadIdx.x;
    const int stride = gridDim.x * blockDim.x;
    for (int i = tid; i < N_NODES; i += stride) {
        const float v = node_sum[i];
        acc += v * v;
    }
    acc = wave_reduce(acc);
    if ((threadIdx.x & 63) == 0) fadd_agent(ws + 5, acc);
}

extern "C" void kernel_launch(void* const* d_in, const int* in_sizes, int n_in,
                              void* d_out, int out_size, void* d_ws, size_t ws_size,
                              hipStream_t stream) {
    const float*  nf     = (const float*)d_in[0];
    const void*   eidx   = d_in[1];
    const float*  logits = (const float*)d_in[2];
    const float2* params = (const float2*)d_in[3];
    float* ws  = (float*)d_ws;
    float* out = (float*)d_out;

    const size_t need = (size_t)WS_FLOATS * sizeof(float);   // ~64.3 MB

    if (ws_size >= need) {
        hipMemsetAsync(d_ws, 0, 256, stream);
        const int prep_blocks = (N_EDGES + PREP_EPB - 1) / PREP_EPB;  // 1563
        prep_kernel<<<prep_blocks, 256, 0, stream>>>(nf, eidx, logits, params, ws);
        scatter_kernel<<<NCHUNK * NSLICE, 256, 0, stream>>>(ws);
        kcl_kernel<<<(N_NODES + 255) / 256, 256, 0, stream>>>(ws);
    } else {
        hipMemsetAsync(d_ws, 0, 256 + (size_t)N_NODES * sizeof(float), stream);
        edge_kernel_fb<<<2048, 256, 0, stream>>>(nf, eidx, logits, params, ws);
        kcl_kernel_fb<<<200, 256, 0, stream>>>(ws);
    }

    final_kernel<<<1, 1, 0, stream>>>(ws, out);
}

// Round 6
// 345.435 us; speedup vs baseline: 1.9707x; 1.4304x over previous
//
#include <hip/hip_runtime.h>
#include <math.h>

#define N_NODES 100000
#define N_EDGES 3200000
#define EPS_F 1e-6f

#define NSLICE  8
#define SLICE_N 12500                     // nodes per slice (8*12500 = 100000)
#define NCHUNK  64
#define CHUNK_E (N_EDGES / NCHUNK)        // 50000 exactly

// prep batching: J edges per thread, static trip count for load batching
#define PREP_J   16
#define PREP_EPB (256 * PREP_J)           // 4096 edges per block

// ws layout (float indices):
//   [1..4]   : sum(p0), sum(p1), sum(p0^2), sum(p1^2)
//   [5]      : sum(node_sum^2)
//   CUR_OFF  : cur[N_EDGES]                       (12.8 MB)
//   IDX_OFF  : packed int2 (src,dst)[N_EDGES]     (25.6 MB)
//   PART_OFF : partials[NCHUNK][N_NODES]          (25.6 MB)
//   V_OFF    : packed v[N_NODES]                  (0.4 MB)
#define CUR_OFF   64
#define IDX_OFF   (CUR_OFF + N_EDGES)
#define PART_OFF  (IDX_OFF + 2 * N_EDGES)
#define V_OFF     (PART_OFF + NCHUNK * N_NODES)
#define WS_FLOATS (V_OFF + N_NODES)

__device__ __forceinline__ float wave_reduce(float v) {
    #pragma unroll
    for (int off = 32; off > 0; off >>= 1) v += __shfl_down(v, off, 64);
    return v;
}

__device__ __forceinline__ void fadd_agent(float* p, float v) {
    unsafeAtomicAdd(p, v);   // only scalar-acc updates
}

// ---------------- pass 0: pack v = nf[:,0] into a dense 400 KB table ----------------
__global__ __launch_bounds__(256) void packv_kernel(
    const float* __restrict__ nf, float* __restrict__ ws)
{
    const int i = blockIdx.x * blockDim.x + threadIdx.x;
    if (i < N_NODES) ws[V_OFF + i] = nf[i * 4];
}

// ---------------- pass A: per-edge compute + pack, high-MLP ----------------
__global__ __launch_bounds__(256, 2) void prep_kernel(
    const void*   __restrict__ eidx,
    const float*  __restrict__ logits,
    const float2* __restrict__ params,
    float*        __restrict__ ws)
{
    const int*       i32 = (const int*)eidx;
    const long long* i64 = (const long long*)eidx;

    // int64 values < 2^31 have zero hi-words at every odd int32 slot;
    // int32 has random node ids there (16 zeros ~ impossible).
    int any = 0;
    #pragma unroll
    for (int k = 1; k < 32; k += 2) any |= i32[k];
    const bool is32 = (any != 0);

    const float* vtab   = ws + V_OFF;
    float*       cur_out = ws + CUR_OFF;
    int2*        idx_out = (int2*)(ws + IDX_OFF);
    float*       acc     = ws + 1;

    const int e_base = blockIdx.x * PREP_EPB + threadIdx.x;

    int   srcv[PREP_J], dstv[PREP_J];
    float vsv[PREP_J], vdv[PREP_J], lgv[PREP_J];
    float2 epv[PREP_J];

    // Stage 1: all index loads (coalesced; clamped so loads stay unconditional)
    #pragma unroll
    for (int j = 0; j < PREP_J; ++j) {
        int e = e_base + j * 256;
        e = (e < N_EDGES) ? e : (N_EDGES - 1);
        if (is32) {
            srcv[j] = i32[e];
            dstv[j] = i32[N_EDGES + e];
        } else {
            srcv[j] = (int)i64[e];
            dstv[j] = (int)i64[N_EDGES + e];
        }
    }
    // Stage 2: 2*J independent gathers in flight (32-bit offsets, dense table)
    #pragma unroll
    for (int j = 0; j < PREP_J; ++j) {
        vsv[j] = vtab[srcv[j]];
        vdv[j] = vtab[dstv[j]];
    }
    // Stage 3: streaming loads (independent of stage 2)
    #pragma unroll
    for (int j = 0; j < PREP_J; ++j) {
        int e = e_base + j * 256;
        e = (e < N_EDGES) ? e : (N_EDGES - 1);
        lgv[j] = logits[e];
        epv[j] = params[e];
    }
    // Stage 4: compute + masked stores + masked sums
    float s0 = 0.f, s1 = 0.f, q0 = 0.f, q1 = 0.f;
    #pragma unroll
    for (int j = 0; j < PREP_J; ++j) {
        const int  e  = e_base + j * 256;
        const bool ok = (e < N_EDGES);
        const float2 ep = epv[j];
        const float p   = 1.0f / (1.0f + __expf(-lgv[j]));
        const float cur = fabsf(vsv[j] - vdv[j]) / (ep.x + ep.y + EPS_F) * p;
        if (ok) {
            cur_out[e] = cur;
            idx_out[e] = make_int2(srcv[j], dstv[j]);
            s0 += ep.x; s1 += ep.y;
            q0 += ep.x * ep.x; q1 += ep.y * ep.y;
        }
    }

    s0 = wave_reduce(s0);
    s1 = wave_reduce(s1);
    q0 = wave_reduce(q0);
    q1 = wave_reduce(q1);
    if ((threadIdx.x & 63) == 0) {
        fadd_agent(acc + 0, s0);
        fadd_agent(acc + 1, s1);
        fadd_agent(acc + 2, q0);
        fadd_agent(acc + 3, q1);
    }
}

// ---------------- pass B: LDS-binned scatter, 4x ILP-batched ----------------
__global__ __launch_bounds__(256) void scatter_kernel(float* __restrict__ ws)
{
    __shared__ float bins[SLICE_N];   // 50 KB

    const int s  = blockIdx.x & (NSLICE - 1);   // slice
    const int c  = blockIdx.x >> 3;             // edge chunk
    const int lo = s * SLICE_N;

    for (int j = threadIdx.x; j < SLICE_N; j += 256) bins[j] = 0.f;
    __syncthreads();

    const int2*  idx = (const int2*)(ws + IDX_OFF);
    const float* cur = ws + CUR_OFF;

    const int e0 = c * CHUNK_E;
    const int e1 = e0 + CHUNK_E;

    for (int base = e0 + threadIdx.x; base < e1; base += 1024) {
        int2  sd4[4];
        float v4[4];
        #pragma unroll
        for (int k = 0; k < 4; ++k) {
            int e = base + k * 256;
            e = (e < e1) ? e : (e1 - 1);   // clamp: loads stay unconditional
            sd4[k] = idx[e];
            v4[k]  = cur[e];
        }
        #pragma unroll
        for (int k = 0; k < 4; ++k) {
            if (base + k * 256 < e1) {
                const unsigned ds = (unsigned)(sd4[k].y - lo);
                const unsigned ss = (unsigned)(sd4[k].x - lo);
                if (ds < SLICE_N) atomicAdd(&bins[ds],  v4[k]);
                if (ss < SLICE_N) atomicAdd(&bins[ss], -v4[k]);
            }
        }
    }
    __syncthreads();

    float* p = ws + PART_OFF + (size_t)c * N_NODES + lo;
    for (int j = threadIdx.x; j < SLICE_N; j += 256) p[j] = bins[j];
}

// ---------------- pass C: merge partials, sum of squares ----------------
__global__ __launch_bounds__(256) void kcl_kernel(float* __restrict__ ws)
{
    const int i = blockIdx.x * blockDim.x + threadIdx.x;
    float acc = 0.f;
    if (i < N_NODES) {
        const float* p = ws + PART_OFF + i;
        float s = 0.f;
        #pragma unroll 8
        for (int c = 0; c < NCHUNK; ++c) s += p[(size_t)c * N_NODES];
        acc = s * s;
    }
    acc = wave_reduce(acc);
    if ((threadIdx.x & 63) == 0) fadd_agent(ws + 5, acc);
}

__global__ void final_kernel(const float* __restrict__ ws, float* __restrict__ out)
{
    const float s0 = ws[1], s1 = ws[2], q0 = ws[3], q1 = ws[4], k = ws[5];
    const float n  = (float)N_EDGES;
    const float var0 = (q0 - s0 * s0 / n) / (n - 1.0f);
    const float var1 = (q1 - s1 * s1 / n) / (n - 1.0f);
    out[0] = k / (float)N_NODES + 0.5f * (var0 + var1);
}

// ---------------- fallback (ws too small): agent-atomic scatter ----------------
#define FB_NODE_OFF 64
__global__ __launch_bounds__(256) void edge_kernel_fb(
    const float*  __restrict__ nf,
    const void*   __restrict__ eidx,
    const float*  __restrict__ logits,
    const float2* __restrict__ params,
    float*        __restrict__ ws)
{
    const int*       i32 = (const int*)eidx;
    const long long* i64 = (const long long*)eidx;
    int any = 0;
    #pragma unroll
    for (int k = 1; k < 32; k += 2) any |= i32[k];
    const bool is32 = (any != 0);

    float* node_sum = ws + FB_NODE_OFF;
    float* acc      = ws + 1;

    float s0 = 0.f, s1 = 0.f, q0 = 0.f, q1 = 0.f;
    const int tid    = blockIdx.x * blockDim.x + threadIdx.x;
    const int stride = gridDim.x * blockDim.x;
    for (int i = tid; i < N_EDGES; i += stride) {
        int src, dst;
        if (is32) { src = i32[i]; dst = i32[N_EDGES + i]; }
        else      { src = (int)i64[i]; dst = (int)i64[N_EDGES + i]; }
        const float2 ep = params[i];
        const float  p  = 1.0f / (1.0f + __expf(-logits[i]));
        const float cur = fabsf(nf[src * 4] - nf[dst * 4]) / (ep.x + ep.y + EPS_F) * p;
        fadd_agent(node_sum + dst,  cur);
        fadd_agent(node_sum + src, -cur);
        s0 += ep.x; s1 += ep.y; q0 += ep.x * ep.x; q1 += ep.y * ep.y;
    }
    s0 = wave_reduce(s0); s1 = wave_reduce(s1);
    q0 = wave_reduce(q0); q1 = wave_reduce(q1);
    if ((threadIdx.x & 63) == 0) {
        fadd_agent(acc + 0, s0); fadd_agent(acc + 1, s1);
        fadd_agent(acc + 2, q0); fadd_agent(acc + 3, q1);
    }
}

__global__ __launch_bounds__(256) void kcl_kernel_fb(float* __restrict__ ws)
{
    const float* node_sum = ws + FB_NODE_OFF;
    float acc = 0.f;
    const int tid    = blockIdx.x * blockDim.x + threadIdx.x;
    const int stride = gridDim.x * blockDim.x;
    for (int i = tid; i < N_NODES; i += stride) {
        const float v = node_sum[i];
        acc += v * v;
    }
    acc = wave_reduce(acc);
    if ((threadIdx.x & 63) == 0) fadd_agent(ws + 5, acc);
}

extern "C" void kernel_launch(void* const* d_in, const int* in_sizes, int n_in,
                              void* d_out, int out_size, void* d_ws, size_t ws_size,
                              hipStream_t stream) {
    const float*  nf     = (const float*)d_in[0];
    const void*   eidx   = d_in[1];
    const float*  logits = (const float*)d_in[2];
    const float2* params = (const float2*)d_in[3];
    float* ws  = (float*)d_ws;
    float* out = (float*)d_out;

    const size_t need = (size_t)WS_FLOATS * sizeof(float);   // ~64.7 MB

    if (ws_size >= need) {
        hipMemsetAsync(d_ws, 0, 256, stream);
        packv_kernel<<<(N_NODES + 255) / 256, 256, 0, stream>>>(nf, ws);
        const int prep_blocks = (N_EDGES + PREP_EPB - 1) / PREP_EPB;  // 782
        prep_kernel<<<prep_blocks, 256, 0, stream>>>(eidx, logits, params, ws);
        scatter_kernel<<<NCHUNK * NSLICE, 256, 0, stream>>>(ws);
        kcl_kernel<<<(N_NODES + 255) / 256, 256, 0, stream>>>(ws);
    } else {
        hipMemsetAsync(d_ws, 0, 256 + (size_t)N_NODES * sizeof(float), stream);
        edge_kernel_fb<<<2048, 256, 0, stream>>>(nf, eidx, logits, params, ws);
        kcl_kernel_fb<<<200, 256, 0, stream>>>(ws);
    }

    final_kernel<<<1, 1, 0, stream>>>(ws, out);
}